// Round 2
// baseline (189.140 us; speedup 1.0000x reference)
//
#include <hip/hip_runtime.h>

#define WPAD 12   // weight row stride (floats): 48B, 16B-aligned for float4 reads

// ---- prep: pad x_s (10-float rows) into 16-float (64B) rows ----
__global__ __launch_bounds__(256) void pad_xs_kernel(const float* __restrict__ xs,
                                                     float* __restrict__ dst, int n2) {
    // n2 = N_S * 5 float2 elements
    int i = blockIdx.x * 256 + threadIdx.x;
    if (i < n2) {
        int row = i / 5, col = i % 5;
        float2 v = ((const float2*)xs)[i];
        ((float2*)dst)[row * 8 + col] = v;   // dst row = 16 floats = 8 float2
    }
}

// ---- prep: pad x_t (5-float rows) into 8-float (32B) rows ----
__global__ __launch_bounds__(256) void pad_xt_kernel(const float* __restrict__ xt,
                                                     float* __restrict__ dst, int n) {
    // n = N_T * 5 floats
    int i = blockIdx.x * 256 + threadIdx.x;
    if (i < n) {
        int row = i / 5, col = i % 5;
        dst[row * 8 + col] = xt[i];
    }
}

template<bool PADDED>
__global__ __launch_bounds__(256) void edge_mlp(
    const float* __restrict__ xs,   // PADDED: 16-float rows, else 10-float rows
    const float* __restrict__ xt,   // PADDED: 8-float rows, else 5-float rows
    const int* __restrict__ src,
    const int* __restrict__ tgt,
    const float* __restrict__ ea,
    const float* __restrict__ u,
    const int* __restrict__ be,
    const float* __restrict__ W1,
    const float* __restrict__ b1,
    const float* __restrict__ W2,
    const float* __restrict__ b2,
    float* __restrict__ out, int E)
{
    __shared__ float sW1[25 * WPAD];  // rows 0..24 of W1 (x_s, x_t, edge_attr parts)
    __shared__ float sW2[10 * WPAD];
    __shared__ float sUp[16 * WPAD];  // U' = u @ W1[25:35] + b1  (B=16 graphs)
    __shared__ float sb2[16];
    __shared__ float stage[2560];     // 256 edges x 10 floats; reused ea-in then out

    const int t = threadIdx.x;

    // weights -> LDS (padded rows)
    for (int i = t; i < 250; i += 256) sW1[(i / 10) * WPAD + (i % 10)] = W1[i];
    for (int i = t; i < 100; i += 256) sW2[(i / 10) * WPAD + (i % 10)] = W2[i];
    if (t < 10) sb2[t] = b2[t];

    // U' = u @ W1[25:35] + b1  (160 entries, one per thread)
    if (t < 160) {
        const int b = t / 10, j = t % 10;
        float acc = b1[j];
        #pragma unroll
        for (int k = 0; k < 10; ++k) acc += u[b * 10 + k] * W1[(25 + k) * 10 + j];
        sUp[b * WPAD + j] = acc;
    }

    // stage this block's edge_attr chunk, fully coalesced float4
    const long long base_f = (long long)blockIdx.x * 2560;
    const long long totalf = (long long)E * 10;
    const bool full = (base_f + 2560) <= totalf;
    if (full) {
        const float4* ea4 = (const float4*)(ea + base_f);
        for (int i = t; i < 640; i += 256) ((float4*)stage)[i] = ea4[i];
    } else {
        for (int i = t; i < 2560; i += 256)
            if (base_f + i < totalf) stage[i] = ea[base_f + i];
    }
    __syncthreads();

    const int e = blockIdx.x * 256 + t;
    const bool valid = e < E;
    int is = 0, it = 0, ib = 0;
    if (valid) { is = src[e]; it = tgt[e]; ib = be[e]; }

    // ---- gather 25 features (x_s 10, x_t 5, edge_attr 10) ----
    float f[25];
    if (PADDED) {
        const float4* p = (const float4*)xs + (size_t)is * 4;   // 64B row, one line
        float4 a = p[0];
        float4 b = p[1];
        float2 c = ((const float2*)xs)[(size_t)is * 8 + 4];
        f[0] = a.x; f[1] = a.y; f[2] = a.z; f[3] = a.w;
        f[4] = b.x; f[5] = b.y; f[6] = b.z; f[7] = b.w;
        f[8] = c.x; f[9] = c.y;
        const float4* q = (const float4*)xt + (size_t)it * 2;   // 32B row
        float4 d = q[0];
        float  d4 = xt[(size_t)it * 8 + 4];
        f[10] = d.x; f[11] = d.y; f[12] = d.z; f[13] = d.w; f[14] = d4;
    } else {
        const float* ps = xs + (size_t)is * 10;
        #pragma unroll
        for (int i = 0; i < 5; ++i) {
            float2 v = *(const float2*)(ps + 2 * i);
            f[2 * i] = v.x; f[2 * i + 1] = v.y;
        }
        const float* pt = xt + (size_t)it * 5;
        #pragma unroll
        for (int i = 0; i < 5; ++i) f[10 + i] = pt[i];
    }
    #pragma unroll
    for (int i = 0; i < 5; ++i) {
        float2 v = *(const float2*)&stage[t * 10 + 2 * i];
        f[15 + 2 * i] = v.x; f[16 + 2 * i] = v.y;
    }

    // ---- layer 1: h = U'[ib] + f @ W1[0:25] ----
    float h[10];
    {
        float4 a = *(const float4*)&sUp[ib * WPAD];
        float4 b = *(const float4*)&sUp[ib * WPAD + 4];
        float2 c = *(const float2*)&sUp[ib * WPAD + 8];
        h[0] = a.x; h[1] = a.y; h[2] = a.z; h[3] = a.w;
        h[4] = b.x; h[5] = b.y; h[6] = b.z; h[7] = b.w;
        h[8] = c.x; h[9] = c.y;
    }
    #pragma unroll
    for (int k = 0; k < 25; ++k) {
        const float fk = f[k];
        const float4 wa = *(const float4*)&sW1[k * WPAD];
        const float4 wb = *(const float4*)&sW1[k * WPAD + 4];
        const float2 wc = *(const float2*)&sW1[k * WPAD + 8];
        h[0] += fk * wa.x; h[1] += fk * wa.y; h[2] += fk * wa.z; h[3] += fk * wa.w;
        h[4] += fk * wb.x; h[5] += fk * wb.y; h[6] += fk * wb.z; h[7] += fk * wb.w;
        h[8] += fk * wc.x; h[9] += fk * wc.y;
    }
    #pragma unroll
    for (int j = 0; j < 10; ++j) h[j] = (h[j] >= 0.f) ? h[j] : 0.1f * h[j];

    // ---- layer 2 ----
    float o[10];
    #pragma unroll
    for (int j = 0; j < 10; ++j) o[j] = sb2[j];
    #pragma unroll
    for (int k = 0; k < 10; ++k) {
        const float hk = h[k];
        const float4 wa = *(const float4*)&sW2[k * WPAD];
        const float4 wb = *(const float4*)&sW2[k * WPAD + 4];
        const float2 wc = *(const float2*)&sW2[k * WPAD + 8];
        o[0] += hk * wa.x; o[1] += hk * wa.y; o[2] += hk * wa.z; o[3] += hk * wa.w;
        o[4] += hk * wb.x; o[5] += hk * wb.y; o[6] += hk * wb.z; o[7] += hk * wb.w;
        o[8] += hk * wc.x; o[9] += hk * wc.y;
    }

    // ---- stage out rows in LDS, then coalesced float4 store ----
    __syncthreads();   // everyone done reading stage (ea rows)
    #pragma unroll
    for (int i = 0; i < 5; ++i) {
        float2 v; v.x = o[2 * i]; v.y = o[2 * i + 1];
        *(float2*)&stage[t * 10 + 2 * i] = v;
    }
    __syncthreads();
    if (full) {
        float4* out4 = (float4*)(out + base_f);
        for (int i = t; i < 640; i += 256) out4[i] = ((const float4*)stage)[i];
    } else {
        for (int i = t; i < 2560; i += 256)
            if (base_f + i < totalf) out[base_f + i] = stage[i];
    }
}

extern "C" void kernel_launch(void* const* d_in, const int* in_sizes, int n_in,
                              void* d_out, int out_size, void* d_ws, size_t ws_size,
                              hipStream_t stream) {
    const float* x_s      = (const float*)d_in[0];
    const float* x_t      = (const float*)d_in[1];
    const int*   ei       = (const int*)d_in[2];    // (2, E) flat: [src | tgt]
    const float* edge_att = (const float*)d_in[3];
    const float* u        = (const float*)d_in[4];
    const int*   batch_e  = (const int*)d_in[5];
    const float* W1       = (const float*)d_in[6];
    const float* b1       = (const float*)d_in[7];
    const float* W2       = (const float*)d_in[8];
    const float* b2       = (const float*)d_in[9];
    float* out = (float*)d_out;

    const int E   = in_sizes[5];
    const int N_S = in_sizes[0] / 10;
    const int N_T = in_sizes[1] / 5;
    const int blocks = (E + 255) / 256;

    const size_t need = (size_t)N_S * 16 * 4 + (size_t)N_T * 8 * 4;
    if (ws_size >= need) {
        float* xs_pad = (float*)d_ws;
        float* xt_pad = (float*)d_ws + (size_t)N_S * 16;
        int n1 = N_S * 5;   // float2 count
        pad_xs_kernel<<<(n1 + 255) / 256, 256, 0, stream>>>(x_s, xs_pad, n1);
        int n2 = N_T * 5;   // float count
        pad_xt_kernel<<<(n2 + 255) / 256, 256, 0, stream>>>(x_t, xt_pad, n2);
        edge_mlp<true><<<blocks, 256, 0, stream>>>(
            xs_pad, xt_pad, ei, ei + E, edge_att, u, batch_e,
            W1, b1, W2, b2, out, E);
    } else {
        edge_mlp<false><<<blocks, 256, 0, stream>>>(
            x_s, x_t, ei, ei + E, edge_att, u, batch_e,
            W1, b1, W2, b2, out, E);
    }
}

// Round 3
// 139.724 us; speedup vs baseline: 1.3537x; 1.3537x over previous
//
#include <hip/hip_runtime.h>

// ---- prep: pad x_s rows 10->16 floats (64B, one cache line) and x_t rows 5->8 (32B) ----
__global__ __launch_bounds__(256) void pad_tables(const float* __restrict__ xs,
                                                  const float* __restrict__ xt,
                                                  float* __restrict__ xs_pad,
                                                  float* __restrict__ xt_pad,
                                                  int n_s5, int n_t5) {
    int i = blockIdx.x * 256 + threadIdx.x;
    if (i < n_s5) {            // n_s5 = N_S*5 float2 elements
        int row = i / 5, col = i % 5;
        ((float2*)xs_pad)[row * 8 + col] = ((const float2*)xs)[i];
    }
    if (i < n_t5) {            // n_t5 = N_T*5 float elements
        int row = i / 5, col = i % 5;
        xt_pad[row * 8 + col] = xt[i];
    }
}

template<bool PADDED>
__global__ __launch_bounds__(256) void edge_mlp(
    const float* __restrict__ xs,   // PADDED: 16-float rows, else 10
    const float* __restrict__ xt,   // PADDED: 8-float rows, else 5
    const int* __restrict__ src,
    const int* __restrict__ tgt,
    const float* __restrict__ ea,
    const float* __restrict__ u,
    const int* __restrict__ be,
    const float* __restrict__ W1,
    const float* __restrict__ b1,
    const float* __restrict__ W2,
    const float* __restrict__ b2,
    float* __restrict__ out, int E)
{
    __shared__ float sUp[16 * 12];    // U' = u @ W1[25:35] + b1, padded rows
    __shared__ float stage[2560];     // 256 edges x 10 floats; ea in, out later

    const int t = threadIdx.x;

    // U' precompute (per-lane vector loads, once per block, tiny)
    if (t < 160) {
        const int b = t / 10, j = t % 10;
        float acc = b1[j];
        #pragma unroll
        for (int k = 0; k < 10; ++k) acc += u[b * 10 + k] * W1[(25 + k) * 10 + j];
        sUp[b * 12 + j] = acc;
    }

    // stage this block's edge_attr chunk, coalesced float4
    const long long base_f = (long long)blockIdx.x * 2560;
    const long long totalf = (long long)E * 10;
    const bool full = (base_f + 2560) <= totalf;
    if (full) {
        const float4* ea4 = (const float4*)(ea + base_f);
        for (int i = t; i < 640; i += 256) ((float4*)stage)[i] = ea4[i];
    } else {
        for (int i = t; i < 2560; i += 256)
            if (base_f + i < totalf) stage[i] = ea[base_f + i];
    }
    __syncthreads();

    const int e = blockIdx.x * 256 + t;
    const bool valid = e < E;
    int is = 0, it = 0, ib = 0;
    if (valid) { is = src[e]; it = tgt[e]; ib = be[e]; }

    // ---- gather 25 features ----
    float f[25];
    if (PADDED) {
        const float4* p = (const float4*)xs + (size_t)is * 4;   // one 64B line
        float4 a = p[0];
        float4 b = p[1];
        float2 c = ((const float2*)xs)[(size_t)is * 8 + 4];
        f[0] = a.x; f[1] = a.y; f[2] = a.z; f[3] = a.w;
        f[4] = b.x; f[5] = b.y; f[6] = b.z; f[7] = b.w;
        f[8] = c.x; f[9] = c.y;
        const float4* q = (const float4*)xt + (size_t)it * 2;   // 32B row
        float4 d = q[0];
        float  d4 = xt[(size_t)it * 8 + 4];
        f[10] = d.x; f[11] = d.y; f[12] = d.z; f[13] = d.w; f[14] = d4;
    } else {
        const float* ps = xs + (size_t)is * 10;
        #pragma unroll
        for (int i = 0; i < 5; ++i) {
            float2 v = *(const float2*)(ps + 2 * i);
            f[2 * i] = v.x; f[2 * i + 1] = v.y;
        }
        const float* pt = xt + (size_t)it * 5;
        #pragma unroll
        for (int i = 0; i < 5; ++i) f[10 + i] = pt[i];
    }
    #pragma unroll
    for (int i = 0; i < 5; ++i) {
        float2 v = *(const float2*)&stage[t * 10 + 2 * i];
        f[15 + 2 * i] = v.x; f[16 + 2 * i] = v.y;
    }

    // ---- layer 1: h = U'[ib] + f @ W1[0:25] ----
    // W1 reads are wave-uniform with literal offsets -> expect s_load / SGPR operands.
    float h[10];
    {
        float4 a = *(const float4*)&sUp[ib * 12];
        float4 b = *(const float4*)&sUp[ib * 12 + 4];
        float2 c = *(const float2*)&sUp[ib * 12 + 8];
        h[0] = a.x; h[1] = a.y; h[2] = a.z; h[3] = a.w;
        h[4] = b.x; h[5] = b.y; h[6] = b.z; h[7] = b.w;
        h[8] = c.x; h[9] = c.y;
    }
    #pragma unroll
    for (int k = 0; k < 25; ++k) {
        const float fk = f[k];
        #pragma unroll
        for (int j = 0; j < 10; ++j) h[j] += fk * W1[k * 10 + j];
    }
    #pragma unroll
    for (int j = 0; j < 10; ++j) h[j] = (h[j] >= 0.f) ? h[j] : 0.1f * h[j];

    // ---- layer 2: o = h @ W2 + b2 (W2/b2 also scalar-promoted) ----
    float o[10];
    #pragma unroll
    for (int j = 0; j < 10; ++j) o[j] = b2[j];
    #pragma unroll
    for (int k = 0; k < 10; ++k) {
        const float hk = h[k];
        #pragma unroll
        for (int j = 0; j < 10; ++j) o[j] += hk * W2[k * 10 + j];
    }

    // ---- stage out rows in LDS, then coalesced float4 store ----
    __syncthreads();   // all done reading stage (ea rows)
    #pragma unroll
    for (int i = 0; i < 5; ++i) {
        float2 v; v.x = o[2 * i]; v.y = o[2 * i + 1];
        *(float2*)&stage[t * 10 + 2 * i] = v;
    }
    __syncthreads();
    if (full) {
        float4* out4 = (float4*)(out + base_f);
        for (int i = t; i < 640; i += 256) out4[i] = ((const float4*)stage)[i];
    } else {
        for (int i = t; i < 2560; i += 256)
            if (base_f + i < totalf) out[base_f + i] = stage[i];
    }
}

extern "C" void kernel_launch(void* const* d_in, const int* in_sizes, int n_in,
                              void* d_out, int out_size, void* d_ws, size_t ws_size,
                              hipStream_t stream) {
    const float* x_s      = (const float*)d_in[0];
    const float* x_t      = (const float*)d_in[1];
    const int*   ei       = (const int*)d_in[2];    // (2, E) flat: [src | tgt]
    const float* edge_att = (const float*)d_in[3];
    const float* u        = (const float*)d_in[4];
    const int*   batch_e  = (const int*)d_in[5];
    const float* W1       = (const float*)d_in[6];
    const float* b1       = (const float*)d_in[7];
    const float* W2       = (const float*)d_in[8];
    const float* b2       = (const float*)d_in[9];
    float* out = (float*)d_out;

    const int E   = in_sizes[5];
    const int N_S = in_sizes[0] / 10;
    const int N_T = in_sizes[1] / 5;
    const int blocks = (E + 255) / 256;

    const size_t need = (size_t)N_S * 16 * 4 + (size_t)N_T * 8 * 4;
    if (ws_size >= need) {
        float* xs_pad = (float*)d_ws;
        float* xt_pad = (float*)d_ws + (size_t)N_S * 16;
        const int n_s5 = N_S * 5;   // float2 elements
        const int n_t5 = N_T * 5;   // float elements
        const int n    = (n_s5 > n_t5 ? n_s5 : n_t5);
        pad_tables<<<(n + 255) / 256, 256, 0, stream>>>(x_s, x_t, xs_pad, xt_pad, n_s5, n_t5);
        edge_mlp<true><<<blocks, 256, 0, stream>>>(
            xs_pad, xt_pad, ei, ei + E, edge_att, u, batch_e,
            W1, b1, W2, b2, out, E);
    } else {
        edge_mlp<false><<<blocks, 256, 0, stream>>>(
            x_s, x_t, ei, ei + E, edge_att, u, batch_e,
            W1, b1, W2, b2, out, E);
    }
}